// Round 6
// baseline (9641.952 us; speedup 1.0000x reference)
//
#include <hip/hip_runtime.h>
#include <math.h>

#define T_LEN 2048
#define B_SZ  32
#define D_IN  128
#define U_SZ  512
#define N_SZ  256
#define GS    128
#define NT    512

// workspace offsets (in floats)
constexpr size_t OFF_AM  = 0;                                  // Am [256][256]
constexpr size_t OFF_WMM = OFF_AM  + (size_t)N_SZ*N_SZ;        // Wmm [256][512]
constexpr size_t OFF_BW  = OFF_WMM + (size_t)N_SZ*U_SZ;        // bw [512]
constexpr size_t OFF_UX  = OFF_BW  + U_SZ;                     // ux [2048][32]
constexpr size_t OFF_XT  = OFF_UX  + (size_t)T_LEN*B_SZ;       // xT [2048][128][32]
constexpr size_t OFF_S   = OFF_XT  + (size_t)T_LEN*D_IN*B_SZ;  // S [2][768][32]
constexpr size_t OFF_FLG = OFF_S   + (size_t)2*768*B_SZ;       // flags [128][16]

#define FMA4(A, S0, W0) \
  A.x = fmaf(S0, W0.x, A.x); A.y = fmaf(S0, W0.y, A.y); \
  A.z = fmaf(S0, W0.z, A.z); A.w = fmaf(S0, W0.w, A.w);

// one butterfly round over all 28 partial values (same bt, ks^mask/8)
#define REDR(m) \
  a0.x += __shfl_xor(a0.x,(m)); a0.y += __shfl_xor(a0.y,(m)); \
  a0.z += __shfl_xor(a0.z,(m)); a0.w += __shfl_xor(a0.w,(m)); \
  a1.x += __shfl_xor(a1.x,(m)); a1.y += __shfl_xor(a1.y,(m)); \
  a1.z += __shfl_xor(a1.z,(m)); a1.w += __shfl_xor(a1.w,(m)); \
  a2.x += __shfl_xor(a2.x,(m)); a2.y += __shfl_xor(a2.y,(m)); \
  a2.z += __shfl_xor(a2.z,(m)); a2.w += __shfl_xor(a2.w,(m)); \
  a3.x += __shfl_xor(a3.x,(m)); a3.y += __shfl_xor(a3.y,(m)); \
  a3.z += __shfl_xor(a3.z,(m)); a3.w += __shfl_xor(a3.w,(m)); \
  q0.x += __shfl_xor(q0.x,(m)); q0.y += __shfl_xor(q0.y,(m)); \
  q0.z += __shfl_xor(q0.z,(m)); q0.w += __shfl_xor(q0.w,(m)); \
  q1.x += __shfl_xor(q1.x,(m)); q1.y += __shfl_xor(q1.y,(m)); \
  q1.z += __shfl_xor(q1.z,(m)); q1.w += __shfl_xor(q1.w,(m)); \
  sa.x += __shfl_xor(sa.x,(m)); sa.y += __shfl_xor(sa.y,(m)); \
  sa.z += __shfl_xor(sa.z,(m)); sa.w += __shfl_xor(sa.w,(m));

// ---- fence-free cross-XCD primitives: sc1 (agent-scope) ops bypass the
// non-coherent per-XCD L2 and are served at the device coherence point ----
__device__ inline void st_agent_f1(float* p, float f) {
  union { float f; unsigned u; } c; c.f = f;
  __hip_atomic_store((unsigned*)p, c.u, __ATOMIC_RELAXED, __HIP_MEMORY_SCOPE_AGENT);
}
// 16B agent-scope load, issue-only (no wait) — caller must s_waitcnt vmcnt.
// sc1 = same cache-bypass bit __hip_atomic_load(AGENT) emits; per-element
// atomicity is irrelevant (single producer per float + flag handshake).
__device__ inline void ld_agent_f4_issue(float4* dst, const float* p) {
  asm volatile("global_load_dwordx4 %0, %1, off sc1"
               : "=v"(*dst) : "v"(p));
}
// normal 4B load, issue-only (counts in vmcnt like the staged loads)
__device__ inline void ld_f1_issue(float* dst, const float* p) {
  asm volatile("global_load_dword %0, %1, off"
               : "=v"(*dst) : "v"(p));
}

// Am[k][j] = AT[k][j] + I + me[k]*BT[j]   (folds m@me term of u into m-recurrence)
__global__ void k_am(const float* __restrict__ AT, const float* __restrict__ me,
                     const float* __restrict__ BT, float* __restrict__ ws) {
  int k = blockIdx.x, j = threadIdx.x;
  float v = AT[(size_t)k*N_SZ + j] + (k == j ? 1.0f : 0.0f) + me[k]*BT[j];
  ws[OFF_AM + (size_t)k*N_SZ + j] = v;
}

// bw[j] = sum_q BT[q]*Wm[q][j]
__global__ void k_bw(const float* __restrict__ BT, const float* __restrict__ Wm,
                     float* __restrict__ ws) {
  int j = blockIdx.x*256 + threadIdx.x;
  float acc = 0.f;
  for (int q = 0; q < N_SZ; ++q) acc += BT[q]*Wm[(size_t)q*U_SZ + j];
  ws[OFF_BW + j] = acc;
}

// Wmm = Am @ Wm   [256][512]
__global__ void k_wmm(const float* __restrict__ Wm, float* __restrict__ ws) {
  __shared__ float amr[N_SZ];
  int k = blockIdx.x, tid = threadIdx.x;
  amr[tid] = ws[OFF_AM + (size_t)k*N_SZ + tid];
  __syncthreads();
  float acc0 = 0.f, acc1 = 0.f;
  for (int q = 0; q < N_SZ; ++q) {
    float a = amr[q];
    acc0 += a * Wm[(size_t)q*U_SZ + tid];
    acc1 += a * Wm[(size_t)q*U_SZ + tid + 256];
  }
  ws[OFF_WMM + (size_t)k*U_SZ + tid]       = acc0;
  ws[OFF_WMM + (size_t)k*U_SZ + tid + 256] = acc1;
}

// ux[t][b] = x[b][t][:] . ie
__global__ void k_ux(const float* __restrict__ x, const float* __restrict__ ie,
                     float* __restrict__ ws) {
  __shared__ __align__(16) float iel[D_IN];
  __shared__ float red[B_SZ*9];
  int t = blockIdx.x, tid = threadIdx.x;
  if (tid < D_IN) iel[tid] = ie[tid];
  __syncthreads();
  int b = tid >> 3, p = tid & 7;
  const float4* xr = (const float4*)(x + ((size_t)b*T_LEN + t)*D_IN);
  const float4* wr = (const float4*)iel;
  float s = 0.f;
  for (int q = 0; q < 4; ++q) {
    int fi = p + q*8;
    float4 v = xr[fi];
    float4 w = wr[fi];
    s += v.x*w.x + v.y*w.y + v.z*w.z + v.w*w.w;
  }
  red[b*9 + p] = s;
  __syncthreads();
  if (tid < B_SZ) {
    float acc = 0.f;
    for (int p2 = 0; p2 < 8; ++p2) acc += red[tid*9 + p2];
    ws[OFF_UX + (size_t)t*B_SZ + tid] = acc;
  }
}

// xT[t][d][b] = x[b][t][d]
__global__ void k_xt(const float* __restrict__ x, float* __restrict__ ws) {
  __shared__ float tile[B_SZ*33];
  int bid = blockIdx.x;
  int t = bid >> 2, d0 = (bid & 3)*32;
  int tid = threadIdx.x;
  int lo = tid & 31, hi = tid >> 5;
  for (int p = 0; p < 4; ++p) {
    int b = hi + p*8;
    tile[b*33 + lo] = x[((size_t)b*T_LEN + t)*D_IN + d0 + lo];
  }
  __syncthreads();
  float* dst = ws + OFF_XT + ((size_t)t*D_IN + d0)*B_SZ;
  for (int p = 0; p < 4; ++p) {
    int d = hi + p*8;
    dst[(size_t)d*B_SZ + lo] = tile[lo*33 + d];
  }
}

// init: S[0] = [h0 | m0] in [k][b]; zero the barrier flags
__global__ void k_init(const float* __restrict__ h0, const float* __restrict__ mm0,
                       float* __restrict__ ws) {
  int bid = blockIdx.x, tid = threadIdx.x;
  if (bid < 24) {
    for (int i = 0; i < 4; ++i) {
      int e = bid*1024 + i*256 + tid;
      int k = e >> 5, b = e & 31;
      float v = (k < U_SZ) ? h0[(size_t)b*U_SZ + k] : mm0[(size_t)b*N_SZ + (k - U_SZ)];
      ws[OFF_S + e] = v;
    }
  } else {
    for (int idx = tid; idx < GS*16; idx += 256) ws[OFF_FLG + idx] = 0.0f;  // 0u bits
  }
}

// persistent scan: GS=128 blocks x NT=512 threads.
// Block g owns h-cols [g*4, g*4+4) and m-cols [g*2, g*2+2).
// This round vs R4: (1) counted waits — uxv + 12 state loads issued in a
// known asm order, vmcnt(4) covers uxv+sv0..7 (seg1 starts while sv8..11 are
// in flight), vmcnt(0) before seg2; (2) all 512 threads poll (4 pollers per
// flag, drifting phases) to cut detect latency from ~1.3x to ~0.5x the IC
// load latency. Exchange protocol itself unchanged (proven round-0 form).
__global__ __launch_bounds__(NT, 2) void k_scan(
    const float* __restrict__ Wh, const float* __restrict__ Wi,
    const float* __restrict__ he, const float* __restrict__ btv,
    float* __restrict__ ws, float* __restrict__ out)
{
  const int g = blockIdx.x, tid = threadIdx.x;
  const int JH = g*4, JM = g*2;
  const int bt = tid & 7, ks = tid >> 3;   // ks in [0,64)
  const int b0 = bt*4;

  float* uxw = ws + OFF_UX;
  float* xT  = ws + OFF_XT;
  float* Sb  = ws + OFF_S;
  unsigned* flags = (unsigned*)(ws + OFF_FLG);

  __shared__ __align__(16) float Wl[896*4];   // [k][j]: k<512 Wh, <768 Wmm, <896 Wi
  __shared__ __align__(16) float Aml[N_SZ*2]; // [k][jm] m-columns of Am
  __shared__ float Hl[U_SZ];                  // hidden_encoders
  __shared__ __align__(16) float redh[64*20]; // [writer][j*4+b]
  __shared__ __align__(16) float redm[64*12]; // [writer][jm*4+b]
  __shared__ __align__(16) float reds[64*8];  // [writer][b]
  __shared__ float bwl[4], btl[2];

  for (int idx = tid; idx < 896*4; idx += NT) {
    int k = idx >> 2, jj = idx & 3;
    float v;
    if (k < 512)      v = Wh[(size_t)k*U_SZ + JH + jj];
    else if (k < 768) v = ws[OFF_WMM + (size_t)(k-512)*U_SZ + JH + jj];
    else              v = Wi[(size_t)(k-768)*U_SZ + JH + jj];
    Wl[idx] = v;
  }
  for (int idx = tid; idx < N_SZ*2; idx += NT) {
    int k = idx >> 1, jj = idx & 1;
    Aml[idx] = ws[OFF_AM + (size_t)k*N_SZ + JM + jj];
  }
  for (int idx = tid; idx < U_SZ; idx += NT) Hl[idx] = he[idx];
  if (tid < 4) bwl[tid] = ws[OFF_BW + JH + tid];
  if (tid < 2) btl[tid] = btv[JM + tid];
  __syncthreads();

  const float4* Wl4  = (const float4*)Wl;
  const float2* Aml2 = (const float2*)Aml;

  // accumulators: a{0..3} = h-col JH+{0..3} over this thread's 4 batches;
  // q{0,1} = m-col JM+{0,1}; sa = h.he partial.
  float4 a0={0,0,0,0}, a1={0,0,0,0}, a2={0,0,0,0}, a3={0,0,0,0};
  // seg3 for t=0 (x_0 @ Wi), local data only
  {
    const float* xrow = xT;
    #pragma unroll
    for (int i = 12; i < 14; ++i) {
      int kk = i*64 + ks;
      float4 sv = *(const float4*)(xrow + (size_t)(kk - 768)*B_SZ + b0);
      float4 wv = Wl4[kk];
      FMA4(a0, wv.x, sv) FMA4(a1, wv.y, sv) FMA4(a2, wv.z, sv) FMA4(a3, wv.w, sv)
    }
  }

  for (int t = 0; t < T_LEN; ++t) {
    const float* S  = Sb + (size_t)(t & 1)*(768*B_SZ);
    float*       Sn = Sb + (size_t)((t+1) & 1)*(768*B_SZ);

    float4 q0={0,0,0,0}, q1={0,0,0,0};
    float4 sa={0,0,0,0};

    // ---- stage uxv + ALL 12 state vectors in a KNOWN issue order ----
    // (barrier (C) drained vmcnt to 0, so outstanding counts are exact:
    //  after the 13 issues, vmcnt(4) == {uxv, sv0..sv7} complete.)
    float uxv;
    float4 sv0, sv1, sv2, sv3, sv4, sv5, sv6, sv7, sv8, sv9, sv10, sv11;
    ld_f1_issue(&uxv, uxw + (size_t)t*B_SZ + (tid & 31));
    ld_agent_f4_issue(&sv0,  S + (size_t)( 0*64 + ks)*B_SZ + b0);
    ld_agent_f4_issue(&sv1,  S + (size_t)( 1*64 + ks)*B_SZ + b0);
    ld_agent_f4_issue(&sv2,  S + (size_t)( 2*64 + ks)*B_SZ + b0);
    ld_agent_f4_issue(&sv3,  S + (size_t)( 3*64 + ks)*B_SZ + b0);
    ld_agent_f4_issue(&sv4,  S + (size_t)( 4*64 + ks)*B_SZ + b0);
    ld_agent_f4_issue(&sv5,  S + (size_t)( 5*64 + ks)*B_SZ + b0);
    ld_agent_f4_issue(&sv6,  S + (size_t)( 6*64 + ks)*B_SZ + b0);
    ld_agent_f4_issue(&sv7,  S + (size_t)( 7*64 + ks)*B_SZ + b0);
    ld_agent_f4_issue(&sv8,  S + (size_t)( 8*64 + ks)*B_SZ + b0);
    ld_agent_f4_issue(&sv9,  S + (size_t)( 9*64 + ks)*B_SZ + b0);
    ld_agent_f4_issue(&sv10, S + (size_t)(10*64 + ks)*B_SZ + b0);
    ld_agent_f4_issue(&sv11, S + (size_t)(11*64 + ks)*B_SZ + b0);
    asm volatile("s_waitcnt vmcnt(4)" ::: "memory");
    __builtin_amdgcn_sched_barrier(0);   // rule #18: keep FMAs below the wait

    // seg1: k in [0,512): h x Wh (+ local s-partial h.he) — sv8..11 in flight
    #define SEG1(I, SV) { \
      int kk = (I)*64 + ks; \
      float4 wv = Wl4[kk]; \
      float hv = Hl[kk]; \
      FMA4(a0, wv.x, SV) FMA4(a1, wv.y, SV) FMA4(a2, wv.z, SV) FMA4(a3, wv.w, SV) \
      FMA4(sa, hv, SV) }
    SEG1(0, sv0) SEG1(1, sv1) SEG1(2, sv2) SEG1(3, sv3)
    SEG1(4, sv4) SEG1(5, sv5) SEG1(6, sv6) SEG1(7, sv7)
    #undef SEG1
    asm volatile("s_waitcnt vmcnt(0)" ::: "memory");
    __builtin_amdgcn_sched_barrier(0);
    // seg2: k in [512,768): m x Wmm  +  m x Am
    #define SEG2(I, SV) { \
      int kk = (I)*64 + ks; \
      float4 wv = Wl4[kk]; \
      FMA4(a0, wv.x, SV) FMA4(a1, wv.y, SV) FMA4(a2, wv.z, SV) FMA4(a3, wv.w, SV) \
      float2 av = Aml2[kk - 512]; \
      FMA4(q0, av.x, SV) FMA4(q1, av.y, SV) }
    SEG2(8, sv8) SEG2(9, sv9) SEG2(10, sv10) SEG2(11, sv11)
    #undef SEG2

    // in-wave ks-reduction: 3 butterfly rounds (ks^1, ks^2, ks^4 in-wave)
    REDR(8) REDR(16) REDR(32)

    // LDS partials: one writer per (bt, wave) = 64 writers
    if ((tid & 56) == 0) {
      const int wi = bt + 8*(tid >> 6);
      float4* rp = (float4*)(redh + wi*20);
      rp[0] = a0; rp[1] = a1; rp[2] = a2; rp[3] = a3;
      float4* rm = (float4*)(redm + wi*12);
      rm[0] = q0; rm[1] = q1;
      *(float4*)(reds + wi*8) = sa;
    }
    __syncthreads();   // (A)

    // epilogue: tid<128 -> h-cols (be,je); tid in [128,192) -> m-cols (be,jm)
    float val = 0.f;
    if (tid < 192) {
      const int be2 = tid & 31, btb = be2 >> 2, xx = be2 & 3;
      float ssb = uxv;
      #pragma unroll
      for (int wv = 0; wv < 8; ++wv) ssb += reds[(btb + 8*wv)*8 + xx];
      if (tid < 128) {
        const int je = tid >> 5;
        float sum = 0.f;
        #pragma unroll
        for (int wv = 0; wv < 8; ++wv)
          sum += redh[(btb + 8*wv)*20 + je*4 + xx];
        val = tanhf(sum + ssb*bwl[je]);
        st_agent_f1(Sn + (size_t)(JH + je)*B_SZ + be2, val);
      } else {
        const int jm = (tid - 128) >> 5;
        float sum = 0.f;
        #pragma unroll
        for (int wv = 0; wv < 8; ++wv)
          sum += redm[(btb + 8*wv)*12 + jm*4 + xx];
        sum += ssb*btl[jm];
        st_agent_f1(Sn + (size_t)(512 + JM + jm)*B_SZ + be2, sum);
      }
    }
    __syncthreads();   // (B) — implicit vmcnt(0): all Sn sc1 stores are at IC

    // arrival flag ASAP, then off-critical-path work in the barrier shadow
    if (t + 1 < T_LEN && tid == 0)
      __hip_atomic_store(flags + (size_t)g*16, (unsigned)(t + 1),
                         __ATOMIC_RELAXED, __HIP_MEMORY_SCOPE_AGENT);
    if (tid < 128)
      out[((size_t)(tid & 31)*T_LEN + t)*U_SZ + JH + (tid >> 5)] = val;

    a0.x=a0.y=a0.z=a0.w=0.f; a1=a0; a2=a0; a3=a0;
    if (t + 1 < T_LEN) {
      const float* xrow = xT + (size_t)(t+1)*D_IN*B_SZ;
      #pragma unroll
      for (int i = 12; i < 14; ++i) {
        int kk = i*64 + ks;
        float4 sv = *(const float4*)(xrow + (size_t)(kk - 768)*B_SZ + b0);
        float4 wv = Wl4[kk];
        FMA4(a0, wv.x, sv) FMA4(a1, wv.y, sv) FMA4(a2, wv.z, sv) FMA4(a3, wv.w, sv)
      }
      // all 512 threads poll: 4 pollers per flag with drifting phases
      {
        const unsigned* fp = flags + (size_t)(tid & (GS - 1))*16;
        while (__hip_atomic_load(fp, __ATOMIC_RELAXED, __HIP_MEMORY_SCOPE_AGENT)
               < (unsigned)(t + 1)) { }
      }
    }
    __syncthreads();   // (C)
  }
}

extern "C" void kernel_launch(void* const* d_in, const int* in_sizes, int n_in,
                              void* d_out, int out_size, void* d_ws, size_t ws_size,
                              hipStream_t stream) {
  const float* x   = (const float*)d_in[0];
  const float* h0  = (const float*)d_in[1];
  const float* m0  = (const float*)d_in[2];
  const float* ie  = (const float*)d_in[3];
  const float* he  = (const float*)d_in[4];
  const float* me  = (const float*)d_in[5];
  const float* Wi  = (const float*)d_in[6];
  const float* Wh  = (const float*)d_in[7];
  const float* Wm  = (const float*)d_in[8];
  const float* AT  = (const float*)d_in[9];
  const float* BT  = (const float*)d_in[10];
  float* ws  = (float*)d_ws;
  float* out = (float*)d_out;

  k_am  <<<N_SZ, 256, 0, stream>>>(AT, me, BT, ws);
  k_bw  <<<2, 256, 0, stream>>>(BT, Wm, ws);
  k_wmm <<<N_SZ, 256, 0, stream>>>(Wm, ws);
  k_ux  <<<T_LEN, 256, 0, stream>>>(x, ie, ws);
  k_xt  <<<T_LEN*4, 256, 0, stream>>>(x, ws);
  k_init<<<25, 256, 0, stream>>>(h0, m0, ws);
  k_scan<<<GS, NT, 0, stream>>>(Wh, Wi, he, BT, ws, out);
}

// Round 9
// 9569.884 us; speedup vs baseline: 1.0075x; 1.0075x over previous
//
#include <hip/hip_runtime.h>
#include <math.h>

#define T_LEN 2048
#define B_SZ  32
#define D_IN  128
#define U_SZ  512
#define N_SZ  256
#define GS    128
#define NT    512

// workspace offsets (in floats)
constexpr size_t OFF_AM  = 0;                                  // Am [256][256]
constexpr size_t OFF_WMM = OFF_AM  + (size_t)N_SZ*N_SZ;        // Wmm [256][512]
constexpr size_t OFF_BW  = OFF_WMM + (size_t)N_SZ*U_SZ;        // bw [512]
constexpr size_t OFF_UX  = OFF_BW  + U_SZ;                     // ux [2048][32]
constexpr size_t OFF_XT  = OFF_UX  + (size_t)T_LEN*B_SZ;       // xT [2048][128][32]
constexpr size_t OFF_S   = OFF_XT  + (size_t)T_LEN*D_IN*B_SZ;  // S [2][768][32]
constexpr size_t OFF_FLG = OFF_S   + (size_t)2*768*B_SZ;       // flags2 [128][128] u32

#define FMA4(A, S0, W0) \
  A.x = fmaf(S0, W0.x, A.x); A.y = fmaf(S0, W0.y, A.y); \
  A.z = fmaf(S0, W0.z, A.z); A.w = fmaf(S0, W0.w, A.w);

// one butterfly round over all 28 partial values (same bt, ks^mask/8)
#define REDR(m) \
  a0.x += __shfl_xor(a0.x,(m)); a0.y += __shfl_xor(a0.y,(m)); \
  a0.z += __shfl_xor(a0.z,(m)); a0.w += __shfl_xor(a0.w,(m)); \
  a1.x += __shfl_xor(a1.x,(m)); a1.y += __shfl_xor(a1.y,(m)); \
  a1.z += __shfl_xor(a1.z,(m)); a1.w += __shfl_xor(a1.w,(m)); \
  a2.x += __shfl_xor(a2.x,(m)); a2.y += __shfl_xor(a2.y,(m)); \
  a2.z += __shfl_xor(a2.z,(m)); a2.w += __shfl_xor(a2.w,(m)); \
  a3.x += __shfl_xor(a3.x,(m)); a3.y += __shfl_xor(a3.y,(m)); \
  a3.z += __shfl_xor(a3.z,(m)); a3.w += __shfl_xor(a3.w,(m)); \
  q0.x += __shfl_xor(q0.x,(m)); q0.y += __shfl_xor(q0.y,(m)); \
  q0.z += __shfl_xor(q0.z,(m)); q0.w += __shfl_xor(q0.w,(m)); \
  q1.x += __shfl_xor(q1.x,(m)); q1.y += __shfl_xor(q1.y,(m)); \
  q1.z += __shfl_xor(q1.z,(m)); q1.w += __shfl_xor(q1.w,(m)); \
  sa.x += __shfl_xor(sa.x,(m)); sa.y += __shfl_xor(sa.y,(m)); \
  sa.z += __shfl_xor(sa.z,(m)); sa.w += __shfl_xor(sa.w,(m));

// ---- fence-free cross-XCD primitives: sc1 (agent-scope) ops bypass the
// non-coherent per-XCD L2 and are served at the device coherence point ----
__device__ inline void st_agent_f1(float* p, float f) {
  union { float f; unsigned u; } c; c.f = f;
  __hip_atomic_store((unsigned*)p, c.u, __ATOMIC_RELAXED, __HIP_MEMORY_SCOPE_AGENT);
}
// 16B agent-scope load, issue-only (no wait) — caller must s_waitcnt vmcnt.
// sc1 = same cache-bypass bit __hip_atomic_load(AGENT) emits; per-element
// atomicity is irrelevant (single producer per float + flag handshake).
__device__ inline void ld_agent_f4_issue(float4* dst, const float* p) {
  asm volatile("global_load_dwordx4 %0, %1, off sc1"
               : "=v"(*dst) : "v"(p));
}

// Am[k][j] = AT[k][j] + I + me[k]*BT[j]   (folds m@me term of u into m-recurrence)
__global__ void k_am(const float* __restrict__ AT, const float* __restrict__ me,
                     const float* __restrict__ BT, float* __restrict__ ws) {
  int k = blockIdx.x, j = threadIdx.x;
  float v = AT[(size_t)k*N_SZ + j] + (k == j ? 1.0f : 0.0f) + me[k]*BT[j];
  ws[OFF_AM + (size_t)k*N_SZ + j] = v;
}

// bw[j] = sum_q BT[q]*Wm[q][j]
__global__ void k_bw(const float* __restrict__ BT, const float* __restrict__ Wm,
                     float* __restrict__ ws) {
  int j = blockIdx.x*256 + threadIdx.x;
  float acc = 0.f;
  for (int q = 0; q < N_SZ; ++q) acc += BT[q]*Wm[(size_t)q*U_SZ + j];
  ws[OFF_BW + j] = acc;
}

// Wmm = Am @ Wm   [256][512]
__global__ void k_wmm(const float* __restrict__ Wm, float* __restrict__ ws) {
  __shared__ float amr[N_SZ];
  int k = blockIdx.x, tid = threadIdx.x;
  amr[tid] = ws[OFF_AM + (size_t)k*N_SZ + tid];
  __syncthreads();
  float acc0 = 0.f, acc1 = 0.f;
  for (int q = 0; q < N_SZ; ++q) {
    float a = amr[q];
    acc0 += a * Wm[(size_t)q*U_SZ + tid];
    acc1 += a * Wm[(size_t)q*U_SZ + tid + 256];
  }
  ws[OFF_WMM + (size_t)k*U_SZ + tid]       = acc0;
  ws[OFF_WMM + (size_t)k*U_SZ + tid + 256] = acc1;
}

// ux[t][b] = x[b][t][:] . ie
__global__ void k_ux(const float* __restrict__ x, const float* __restrict__ ie,
                     float* __restrict__ ws) {
  __shared__ __align__(16) float iel[D_IN];
  __shared__ float red[B_SZ*9];
  int t = blockIdx.x, tid = threadIdx.x;
  if (tid < D_IN) iel[tid] = ie[tid];
  __syncthreads();
  int b = tid >> 3, p = tid & 7;
  const float4* xr = (const float4*)(x + ((size_t)b*T_LEN + t)*D_IN);
  const float4* wr = (const float4*)iel;
  float s = 0.f;
  for (int q = 0; q < 4; ++q) {
    int fi = p + q*8;
    float4 v = xr[fi];
    float4 w = wr[fi];
    s += v.x*w.x + v.y*w.y + v.z*w.z + v.w*w.w;
  }
  red[b*9 + p] = s;
  __syncthreads();
  if (tid < B_SZ) {
    float acc = 0.f;
    for (int p2 = 0; p2 < 8; ++p2) acc += red[tid*9 + p2];
    ws[OFF_UX + (size_t)t*B_SZ + tid] = acc;
  }
}

// xT[t][d][b] = x[b][t][d]
__global__ void k_xt(const float* __restrict__ x, float* __restrict__ ws) {
  __shared__ float tile[B_SZ*33];
  int bid = blockIdx.x;
  int t = bid >> 2, d0 = (bid & 3)*32;
  int tid = threadIdx.x;
  int lo = tid & 31, hi = tid >> 5;
  for (int p = 0; p < 4; ++p) {
    int b = hi + p*8;
    tile[b*33 + lo] = x[((size_t)b*T_LEN + t)*D_IN + d0 + lo];
  }
  __syncthreads();
  float* dst = ws + OFF_XT + ((size_t)t*D_IN + d0)*B_SZ;
  for (int p = 0; p < 4; ++p) {
    int d = hi + p*8;
    dst[(size_t)d*B_SZ + lo] = tile[lo*33 + d];
  }
}

// init: S[0] = [h0 | m0] in [k][b]; zero the broadcast flag matrix
__global__ void k_init(const float* __restrict__ h0, const float* __restrict__ mm0,
                       float* __restrict__ ws) {
  int bid = blockIdx.x, tid = threadIdx.x;
  if (bid < 24) {
    for (int i = 0; i < 4; ++i) {
      int e = bid*1024 + i*256 + tid;
      int k = e >> 5, b = e & 31;
      float v = (k < U_SZ) ? h0[(size_t)b*U_SZ + k] : mm0[(size_t)b*N_SZ + (k - U_SZ)];
      ws[OFF_S + e] = v;
    }
  } else {
    for (int idx = tid; idx < GS*GS; idx += 256) ws[OFF_FLG + idx] = 0.0f;  // 0u bits
  }
}

// persistent scan: GS=128 blocks x NT=512 threads.
// Block g owns h-cols [g*4, g*4+4) and m-cols [g*2, g*2+2).
// Base = R4 (9.19ms measured). ONE change: broadcast flag topology.
// Old: flag[g] polled by 1 thread in EVERY block -> 128 remote readers
// spinning on one IC line (~1 read/7cy, saturated); producer's epoch store
// and detection queue behind the storm (R5 measured the contention slope:
// 4x pollers/line = +440cy/step). New: flags2[consumer][producer], 4B
// stride. Producer g stores epoch to flags2[c*128+g] for all c (128
// scattered fire-and-forget stores, after barrier B so data-before-flag
// ordering at the IC is preserved). Consumer g polls only its own row
// flags2[g*128+tid] — wave-coalesced, private lines, ~2 reads/line/RT.
__global__ __launch_bounds__(NT, 2) void k_scan(
    const float* __restrict__ Wh, const float* __restrict__ Wi,
    const float* __restrict__ he, const float* __restrict__ btv,
    float* __restrict__ ws, float* __restrict__ out)
{
  const int g = blockIdx.x, tid = threadIdx.x;
  const int JH = g*4, JM = g*2;
  const int bt = tid & 7, ks = tid >> 3;   // ks in [0,64)
  const int b0 = bt*4;

  float* uxw = ws + OFF_UX;
  float* xT  = ws + OFF_XT;
  float* Sb  = ws + OFF_S;
  unsigned* flags = (unsigned*)(ws + OFF_FLG);

  __shared__ __align__(16) float Wl[896*4];   // [k][j]: k<512 Wh, <768 Wmm, <896 Wi
  __shared__ __align__(16) float Aml[N_SZ*2]; // [k][jm] m-columns of Am
  __shared__ float Hl[U_SZ];                  // hidden_encoders
  __shared__ __align__(16) float redh[64*20]; // [writer][j*4+b]
  __shared__ __align__(16) float redm[64*12]; // [writer][jm*4+b]
  __shared__ __align__(16) float reds[64*8];  // [writer][b]
  __shared__ float bwl[4], btl[2];

  for (int idx = tid; idx < 896*4; idx += NT) {
    int k = idx >> 2, jj = idx & 3;
    float v;
    if (k < 512)      v = Wh[(size_t)k*U_SZ + JH + jj];
    else if (k < 768) v = ws[OFF_WMM + (size_t)(k-512)*U_SZ + JH + jj];
    else              v = Wi[(size_t)(k-768)*U_SZ + JH + jj];
    Wl[idx] = v;
  }
  for (int idx = tid; idx < N_SZ*2; idx += NT) {
    int k = idx >> 1, jj = idx & 1;
    Aml[idx] = ws[OFF_AM + (size_t)k*N_SZ + JM + jj];
  }
  for (int idx = tid; idx < U_SZ; idx += NT) Hl[idx] = he[idx];
  if (tid < 4) bwl[tid] = ws[OFF_BW + JH + tid];
  if (tid < 2) btl[tid] = btv[JM + tid];
  __syncthreads();

  const float4* Wl4  = (const float4*)Wl;
  const float2* Aml2 = (const float2*)Aml;

  // accumulators: a{0..3} = h-col JH+{0..3} over this thread's 4 batches;
  // q{0,1} = m-col JM+{0,1}; sa = h.he partial.
  float4 a0={0,0,0,0}, a1={0,0,0,0}, a2={0,0,0,0}, a3={0,0,0,0};
  // seg3 for t=0 (x_0 @ Wi), local data only
  {
    const float* xrow = xT;
    #pragma unroll
    for (int i = 12; i < 14; ++i) {
      int kk = i*64 + ks;
      float4 sv = *(const float4*)(xrow + (size_t)(kk - 768)*B_SZ + b0);
      float4 wv = Wl4[kk];
      FMA4(a0, wv.x, sv) FMA4(a1, wv.y, sv) FMA4(a2, wv.z, sv) FMA4(a3, wv.w, sv)
    }
  }

  for (int t = 0; t < T_LEN; ++t) {
    const float* S  = Sb + (size_t)(t & 1)*(768*B_SZ);
    float*       Sn = Sb + (size_t)((t+1) & 1)*(768*B_SZ);

    float uxv = uxw[(size_t)t*B_SZ + (tid & 31)];

    float4 q0={0,0,0,0}, q1={0,0,0,0};
    float4 sa={0,0,0,0};

    // ---- stage ALL 12 state vectors (16B sc1 loads), one wait, then FMA ----
    float4 sv0, sv1, sv2, sv3, sv4, sv5, sv6, sv7, sv8, sv9, sv10, sv11;
    ld_agent_f4_issue(&sv0,  S + (size_t)( 0*64 + ks)*B_SZ + b0);
    ld_agent_f4_issue(&sv1,  S + (size_t)( 1*64 + ks)*B_SZ + b0);
    ld_agent_f4_issue(&sv2,  S + (size_t)( 2*64 + ks)*B_SZ + b0);
    ld_agent_f4_issue(&sv3,  S + (size_t)( 3*64 + ks)*B_SZ + b0);
    ld_agent_f4_issue(&sv4,  S + (size_t)( 4*64 + ks)*B_SZ + b0);
    ld_agent_f4_issue(&sv5,  S + (size_t)( 5*64 + ks)*B_SZ + b0);
    ld_agent_f4_issue(&sv6,  S + (size_t)( 6*64 + ks)*B_SZ + b0);
    ld_agent_f4_issue(&sv7,  S + (size_t)( 7*64 + ks)*B_SZ + b0);
    ld_agent_f4_issue(&sv8,  S + (size_t)( 8*64 + ks)*B_SZ + b0);
    ld_agent_f4_issue(&sv9,  S + (size_t)( 9*64 + ks)*B_SZ + b0);
    ld_agent_f4_issue(&sv10, S + (size_t)(10*64 + ks)*B_SZ + b0);
    ld_agent_f4_issue(&sv11, S + (size_t)(11*64 + ks)*B_SZ + b0);
    asm volatile("s_waitcnt vmcnt(0)" ::: "memory");
    __builtin_amdgcn_sched_barrier(0);   // rule #18: keep FMAs below the wait

    // seg1: k in [0,512): h x Wh (+ local s-partial h.he)
    #define SEG1(I, SV) { \
      int kk = (I)*64 + ks; \
      float4 wv = Wl4[kk]; \
      float hv = Hl[kk]; \
      FMA4(a0, wv.x, SV) FMA4(a1, wv.y, SV) FMA4(a2, wv.z, SV) FMA4(a3, wv.w, SV) \
      FMA4(sa, hv, SV) }
    SEG1(0, sv0) SEG1(1, sv1) SEG1(2, sv2) SEG1(3, sv3)
    SEG1(4, sv4) SEG1(5, sv5) SEG1(6, sv6) SEG1(7, sv7)
    #undef SEG1
    // seg2: k in [512,768): m x Wmm  +  m x Am
    #define SEG2(I, SV) { \
      int kk = (I)*64 + ks; \
      float4 wv = Wl4[kk]; \
      FMA4(a0, wv.x, SV) FMA4(a1, wv.y, SV) FMA4(a2, wv.z, SV) FMA4(a3, wv.w, SV) \
      float2 av = Aml2[kk - 512]; \
      FMA4(q0, av.x, SV) FMA4(q1, av.y, SV) }
    SEG2(8, sv8) SEG2(9, sv9) SEG2(10, sv10) SEG2(11, sv11)
    #undef SEG2

    // in-wave ks-reduction: 3 butterfly rounds (ks^1, ks^2, ks^4 in-wave)
    REDR(8) REDR(16) REDR(32)

    // LDS partials: one writer per (bt, wave) = 64 writers
    if ((tid & 56) == 0) {
      const int wi = bt + 8*(tid >> 6);
      float4* rp = (float4*)(redh + wi*20);
      rp[0] = a0; rp[1] = a1; rp[2] = a2; rp[3] = a3;
      float4* rm = (float4*)(redm + wi*12);
      rm[0] = q0; rm[1] = q1;
      *(float4*)(reds + wi*8) = sa;
    }
    __syncthreads();   // (A)

    // epilogue: tid<128 -> h-cols (be,je); tid in [128,192) -> m-cols (be,jm)
    float val = 0.f;
    if (tid < 192) {
      const int be2 = tid & 31, btb = be2 >> 2, xx = be2 & 3;
      float ssb = uxv;
      #pragma unroll
      for (int wv = 0; wv < 8; ++wv) ssb += reds[(btb + 8*wv)*8 + xx];
      if (tid < 128) {
        const int je = tid >> 5;
        float sum = 0.f;
        #pragma unroll
        for (int wv = 0; wv < 8; ++wv)
          sum += redh[(btb + 8*wv)*20 + je*4 + xx];
        val = tanhf(sum + ssb*bwl[je]);
        st_agent_f1(Sn + (size_t)(JH + je)*B_SZ + be2, val);
      } else {
        const int jm = (tid - 128) >> 5;
        float sum = 0.f;
        #pragma unroll
        for (int wv = 0; wv < 8; ++wv)
          sum += redm[(btb + 8*wv)*12 + jm*4 + xx];
        sum += ssb*btl[jm];
        st_agent_f1(Sn + (size_t)(512 + JM + jm)*B_SZ + be2, sum);
      }
    }
    __syncthreads();   // (B) — implicit vmcnt(0): all Sn sc1 stores are at IC

    // broadcast arrival flags ASAP: thread tid tells consumer block c=tid
    // (private line flags2[c][g]); then off-critical-path work in the shadow
    if (t + 1 < T_LEN && tid < GS)
      __hip_atomic_store(flags + (size_t)tid*GS + g, (unsigned)(t + 1),
                         __ATOMIC_RELAXED, __HIP_MEMORY_SCOPE_AGENT);
    if (tid < 128)
      out[((size_t)(tid & 31)*T_LEN + t)*U_SZ + JH + (tid >> 5)] = val;

    a0.x=a0.y=a0.z=a0.w=0.f; a1=a0; a2=a0; a3=a0;
    if (t + 1 < T_LEN) {
      const float* xrow = xT + (size_t)(t+1)*D_IN*B_SZ;
      #pragma unroll
      for (int i = 12; i < 14; ++i) {
        int kk = i*64 + ks;
        float4 sv = *(const float4*)(xrow + (size_t)(kk - 768)*B_SZ + b0);
        float4 wv = Wl4[kk];
        FMA4(a0, wv.x, sv) FMA4(a1, wv.y, sv) FMA4(a2, wv.z, sv) FMA4(a3, wv.w, sv)
      }
      // poll OUR OWN flag row (coalesced, no cross-block line sharing)
      if (tid < GS) {
        const unsigned* fp = flags + (size_t)g*GS + tid;
        while (__hip_atomic_load(fp, __ATOMIC_RELAXED, __HIP_MEMORY_SCOPE_AGENT)
               < (unsigned)(t + 1)) { }
      }
    }
    __syncthreads();   // (C)
  }
}

extern "C" void kernel_launch(void* const* d_in, const int* in_sizes, int n_in,
                              void* d_out, int out_size, void* d_ws, size_t ws_size,
                              hipStream_t stream) {
  const float* x   = (const float*)d_in[0];
  const float* h0  = (const float*)d_in[1];
  const float* m0  = (const float*)d_in[2];
  const float* ie  = (const float*)d_in[3];
  const float* he  = (const float*)d_in[4];
  const float* me  = (const float*)d_in[5];
  const float* Wi  = (const float*)d_in[6];
  const float* Wh  = (const float*)d_in[7];
  const float* Wm  = (const float*)d_in[8];
  const float* AT  = (const float*)d_in[9];
  const float* BT  = (const float*)d_in[10];
  float* ws  = (float*)d_ws;
  float* out = (float*)d_out;

  k_am  <<<N_SZ, 256, 0, stream>>>(AT, me, BT, ws);
  k_bw  <<<2, 256, 0, stream>>>(BT, Wm, ws);
  k_wmm <<<N_SZ, 256, 0, stream>>>(Wm, ws);
  k_ux  <<<T_LEN, 256, 0, stream>>>(x, ie, ws);
  k_xt  <<<T_LEN*4, 256, 0, stream>>>(x, ws);
  k_init<<<25, 256, 0, stream>>>(h0, m0, ws);
  k_scan<<<GS, NT, 0, stream>>>(Wh, Wi, he, BT, ws, out);
}